// Round 2
// baseline (1662.538 us; speedup 1.0000x reference)
//
#include <hip/hip_runtime.h>
#include <cstdint>

__device__ __forceinline__ float leaky(float v) { return v > 0.f ? v : 0.2f * v; }

// ---------------- CSR build ----------------

__global__ __launch_bounds__(256) void k_count(const int* __restrict__ dst,
                                               int* __restrict__ indeg, int E) {
  int e = blockIdx.x * 256 + threadIdx.x;
  if (e < E) atomicAdd(&indeg[dst[e]], 1);
}

__global__ __launch_bounds__(256) void k_scan1(const int* __restrict__ indeg,
                                               int* __restrict__ bsums) {
  __shared__ int red[256];
  int t = threadIdx.x;
  int base = blockIdx.x * 1024;
  int s = indeg[base + t] + indeg[base + t + 256] + indeg[base + t + 512] + indeg[base + t + 768];
  red[t] = s;
  __syncthreads();
  for (int off = 128; off > 0; off >>= 1) {
    if (t < off) red[t] += red[t + off];
    __syncthreads();
  }
  if (t == 0) bsums[blockIdx.x] = red[0];
}

__global__ __launch_bounds__(256) void k_scan2(int* __restrict__ bsums, int* __restrict__ row_off,
                                               int N, int E, int nb) {
  __shared__ int sc[256];
  int t = threadIdx.x;
  int v = (t < nb) ? bsums[t] : 0;
  sc[t] = v;
  __syncthreads();
  for (int off = 1; off < 256; off <<= 1) {
    int u = (t >= off) ? sc[t - off] : 0;
    __syncthreads();
    sc[t] += u;
    __syncthreads();
  }
  if (t < nb) bsums[t] = (t == 0) ? 0 : sc[t - 1];
  if (t == 0) row_off[N] = E;
}

__global__ __launch_bounds__(256) void k_scan3(const int* __restrict__ indeg,
                                               const int* __restrict__ bsums,
                                               int* __restrict__ row_off,
                                               int* __restrict__ cursor,
                                               float* __restrict__ dis) {
  __shared__ int sc[256];
  int t = threadIdx.x;
  int base = blockIdx.x * 1024;
  int4 d = *(const int4*)(indeg + base + 4 * t);
  int tot = d.x + d.y + d.z + d.w;
  sc[t] = tot;
  __syncthreads();
  for (int off = 1; off < 256; off <<= 1) {
    int u = (t >= off) ? sc[t - off] : 0;
    __syncthreads();
    sc[t] += u;
    __syncthreads();
  }
  int toff = bsums[blockIdx.x] + ((t == 0) ? 0 : sc[t - 1]);
  int4 ro;
  ro.x = toff;
  ro.y = toff + d.x;
  ro.z = toff + d.x + d.y;
  ro.w = toff + d.x + d.y + d.z;
  *(int4*)(row_off + base + 4 * t) = ro;
  *(int4*)(cursor + base + 4 * t) = ro;
  float4 dv;
  dv.x = rsqrtf((float)(d.x + 1));
  dv.y = rsqrtf((float)(d.y + 1));
  dv.z = rsqrtf((float)(d.z + 1));
  dv.w = rsqrtf((float)(d.w + 1));
  *(float4*)(dis + base + 4 * t) = dv;
}

__global__ __launch_bounds__(256) void k_fill(const int* __restrict__ ei,
                                              int* __restrict__ cursor,
                                              int* __restrict__ csr, int E) {
  int e = blockIdx.x * 256 + threadIdx.x;
  if (e < E) {
    int s = ei[e];
    int d = ei[E + e];
    int pos = atomicAdd(&cursor[d], 1);
    csr[pos] = s;
  }
}

// ---------------- Layer 1 projection: h1 = x @ W1  (N x 384 @ 384 x 32) ----------------
// Block: 256 threads, 512 nodes/block. Per thread: 8 nodes x 8 feats.
// LDS: x chunk [16 k][512 n] XOR-swizzled (conflict-free stage + read), W chunk [16][32].

__global__ __launch_bounds__(256, 4) void k_gemm1(const float* __restrict__ x,
                                                  const float* __restrict__ W1,
                                                  float* __restrict__ h1) {
  __shared__ float xl[16 * 512];
  __shared__ float wl[16 * 32];
  int t = threadIdx.x;
  size_t n0 = (size_t)blockIdx.x * 512;
  int fg = t & 3;   // feats fg*8 .. fg*8+7
  int ng = t >> 2;  // nodes ng + 64*i
  float acc[8][8];
#pragma unroll
  for (int i = 0; i < 8; i++)
#pragma unroll
    for (int c = 0; c < 8; c++) acc[i][c] = 0.f;

  for (int kc = 0; kc < 384; kc += 16) {
    __syncthreads();
    // stage x[k][n], swizzled column: col = n ^ ((k>>2)<<2)
#pragma unroll
    for (int i = 0; i < 8; i++) {
      int idx = i * 256 + t;      // 0..2047 float4 slots
      int k4 = idx & 3;           // which float4 along k
      int n = idx >> 2;           // node 0..511
      float4 v = *(const float4*)(x + (n0 + n) * 384 + kc + k4 * 4);
      int nx = n ^ (k4 << 2);
      xl[(k4 * 4 + 0) * 512 + nx] = v.x;
      xl[(k4 * 4 + 1) * 512 + nx] = v.y;
      xl[(k4 * 4 + 2) * 512 + nx] = v.z;
      xl[(k4 * 4 + 3) * 512 + nx] = v.w;
    }
    if (t < 128) ((float4*)wl)[t] = ((const float4*)(W1 + kc * 32))[t];
    __syncthreads();
#pragma unroll
    for (int k = 0; k < 16; k++) {
      const int K = (k >> 2) << 2;  // compile-time per unrolled k
      float w[8];
#pragma unroll
      for (int c = 0; c < 8; c++) w[c] = wl[k * 32 + fg * 8 + c];
      int ngx = ng ^ K;
#pragma unroll
      for (int i = 0; i < 8; i++) {
        float xv = xl[k * 512 + ngx + 64 * i];
#pragma unroll
        for (int c = 0; c < 8; c++) acc[i][c] = fmaf(xv, w[c], acc[i][c]);
      }
    }
  }
#pragma unroll
  for (int i = 0; i < 8; i++) {
    float* dst = h1 + (n0 + ng + 64 * i) * 32 + fg * 8;
    *(float4*)dst = make_float4(acc[i][0], acc[i][1], acc[i][2], acc[i][3]);
    *((float4*)dst + 1) = make_float4(acc[i][4], acc[i][5], acc[i][6], acc[i][7]);
  }
}

// ---------------- Fused layer-1 aggregation + layer-2 projection ----------------
// Half-wave (32 lanes = 32 feats) per node. After computing
// out1[j] = leaky(agg + b1[j]) in-register, immediately project to 8 feats via
// butterfly reduce (out1 never hits memory): h2[n][c] = sum_j out1[j]*W2[j][c].

__global__ __launch_bounds__(256) void k_agg1_fused(const float* __restrict__ h1,
                                                    const float* __restrict__ dis,
                                                    const int* __restrict__ row_off,
                                                    const int* __restrict__ csr,
                                                    const float* __restrict__ b1,
                                                    const float* __restrict__ W2,
                                                    float* __restrict__ h2) {
  __shared__ float w2s[256];
  int t = threadIdx.x;
  w2s[t] = W2[t];
  __syncthreads();
  int j = t & 31;
  int n = blockIdx.x * 8 + (t >> 5);
  int p = row_off[n], end = row_off[n + 1];
  float dn = dis[n];
  float acc = h1[(size_t)n * 32 + j] * dn;  // self loop (x dn again below -> dn^2)
  for (; p + 2 <= end; p += 2) {
    int s0 = csr[p], s1 = csr[p + 1];
    float d0 = dis[s0], d1 = dis[s1];
    float v0 = h1[(size_t)s0 * 32 + j];
    float v1 = h1[(size_t)s1 * 32 + j];
    acc += v0 * d0 + v1 * d1;
  }
  if (p < end) {
    int s0 = csr[p];
    acc += h1[(size_t)s0 * 32 + j] * dis[s0];
  }
  float o = leaky(acc * dn + b1[j]);
  // project: p[c] = o * W2[j][c]; butterfly-sum over the 32-lane half
  float pr[8];
#pragma unroll
  for (int c = 0; c < 8; c++) pr[c] = o * w2s[j * 8 + c];
#pragma unroll
  for (int off = 1; off < 32; off <<= 1) {
#pragma unroll
    for (int c = 0; c < 8; c++) pr[c] += __shfl_xor(pr[c], off);
  }
  if (j == 0) {
    float* dst = h2 + (size_t)n * 8;
    *(float4*)dst = make_float4(pr[0], pr[1], pr[2], pr[3]);
    *((float4*)dst + 1) = make_float4(pr[4], pr[5], pr[6], pr[7]);
  }
}

// ---------------- Layer 2 aggregation ----------------
// 8 lanes per node, 32 nodes per block.

__global__ __launch_bounds__(256) void k_agg2(const float* __restrict__ h2,
                                              const float* __restrict__ dis,
                                              const int* __restrict__ row_off,
                                              const int* __restrict__ csr,
                                              const float* __restrict__ b2,
                                              float* __restrict__ out2) {
  int t = threadIdx.x;
  int j = t & 7;
  int n = blockIdx.x * 32 + (t >> 3);
  int p = row_off[n], end = row_off[n + 1];
  float dn = dis[n];
  float acc = h2[(size_t)n * 8 + j] * dn;
  for (; p + 2 <= end; p += 2) {
    int s0 = csr[p], s1 = csr[p + 1];
    float d0 = dis[s0], d1 = dis[s1];
    acc += h2[(size_t)s0 * 8 + j] * d0 + h2[(size_t)s1 * 8 + j] * d1;
  }
  if (p < end) {
    int s0 = csr[p];
    acc += h2[(size_t)s0 * 8 + j] * dis[s0];
  }
  out2[(size_t)n * 8 + j] = leaky(acc * dn + b2[j]);
}

// ---------------- Readout: per-graph mean over NPG nodes ----------------

__global__ __launch_bounds__(256) void k_readout(const float* __restrict__ out2,
                                                 float* __restrict__ g, int NPG) {
  __shared__ float red[256];
  int t = threadIdx.x;
  int j = t & 7, r0 = t >> 3;
  const float* base = out2 + (size_t)blockIdx.x * NPG * 8;
  float s = 0.f;
  for (int r = r0; r < NPG; r += 32) s += base[(size_t)r * 8 + j];
  red[t] = s;
  __syncthreads();
  if (t < 8) {
    float tot = 0.f;
    for (int q = 0; q < 32; q++) tot += red[t + 8 * q];
    g[blockIdx.x * 8 + t] = tot / (float)NPG;
  }
}

// ---------------- Final MLP: leaky(g@W3+b3)@W4 + b4 ----------------

__global__ __launch_bounds__(64) void k_mlp(const float* __restrict__ g,
                                            const float* __restrict__ W3,
                                            const float* __restrict__ b3,
                                            const float* __restrict__ W4,
                                            const float* __restrict__ b4,
                                            float* __restrict__ out, int B) {
  int b = threadIdx.x;
  if (b >= B) return;
  float gi[8], t1[8];
#pragma unroll
  for (int k = 0; k < 8; k++) gi[k] = g[b * 8 + k];
#pragma unroll
  for (int jj = 0; jj < 8; jj++) {
    float s = b3[jj];
#pragma unroll
    for (int k = 0; k < 8; k++) s = fmaf(gi[k], W3[k * 8 + jj], s);
    t1[jj] = leaky(s);
  }
#pragma unroll
  for (int jj = 0; jj < 2; jj++) {
    float s = b4[jj];
#pragma unroll
    for (int k = 0; k < 8; k++) s = fmaf(t1[k], W4[k * 2 + jj], s);
    out[b * 2 + jj] = s;
  }
}

extern "C" void kernel_launch(void* const* d_in, const int* in_sizes, int n_in,
                              void* d_out, int out_size, void* d_ws, size_t ws_size,
                              hipStream_t stream) {
  const float* x  = (const float*)d_in[0];
  const int*   ei = (const int*)d_in[1];  // [2][E]: row0=src, row1=dst
  const float* W1 = (const float*)d_in[3];
  const float* b1 = (const float*)d_in[4];
  const float* W2 = (const float*)d_in[5];
  const float* b2 = (const float*)d_in[6];
  const float* W3 = (const float*)d_in[7];
  const float* b3 = (const float*)d_in[8];
  const float* W4 = (const float*)d_in[9];
  const float* b4 = (const float*)d_in[10];

  const int E = in_sizes[1] / 2;
  const int N = in_sizes[2];
  const int B = out_size / 2;
  const int NPG = N / B;
  const int NB = N / 1024;

  // workspace layout with overflow guard (no OOB writes if ws is small)
  size_t off = 0;
  auto place = [&](size_t bytes) {
    size_t p = off;
    off = (off + bytes + 255) & ~(size_t)255;
    return p;
  };
  size_t o_indeg   = place((size_t)N * 4);
  size_t o_dis     = place((size_t)N * 4);
  size_t o_row_off = place(((size_t)N + 1) * 4);
  size_t o_cursor  = place((size_t)N * 4);
  size_t o_csr     = place((size_t)E * 4);
  size_t o_bsums   = place(1024 * 4);
  size_t o_h1      = place((size_t)N * 32 * 4);
  size_t o_h2      = place((size_t)N * 8 * 4);
  size_t o_gbuf    = place((size_t)B * 8 * 4);
  if (off > ws_size) {  // cannot run safely; leave a defined (wrong) output
    hipMemsetAsync(d_out, 0, (size_t)out_size * 4, stream);
    return;
  }
  char* ws = (char*)d_ws;
  int*   indeg   = (int*)(ws + o_indeg);
  float* dis     = (float*)(ws + o_dis);
  int*   row_off = (int*)(ws + o_row_off);
  int*   cursor  = (int*)(ws + o_cursor);
  int*   csr     = (int*)(ws + o_csr);
  int*   bsums   = (int*)(ws + o_bsums);
  float* h1      = (float*)(ws + o_h1);
  float* h2      = (float*)(ws + o_h2);
  float* gbuf    = (float*)(ws + o_gbuf);
  float* out2    = h1;  // h1 dead after k_agg1_fused; safe alias

  hipMemsetAsync(indeg, 0, (size_t)N * 4, stream);
  k_count<<<(E + 255) / 256, 256, 0, stream>>>(ei + E, indeg, E);
  k_scan1<<<NB, 256, 0, stream>>>(indeg, bsums);
  k_scan2<<<1, 256, 0, stream>>>(bsums, row_off, N, E, NB);
  k_scan3<<<NB, 256, 0, stream>>>(indeg, bsums, row_off, cursor, dis);
  k_fill<<<(E + 255) / 256, 256, 0, stream>>>(ei, cursor, csr, E);
  k_gemm1<<<N / 512, 256, 0, stream>>>(x, W1, h1);
  k_agg1_fused<<<N / 8, 256, 0, stream>>>(h1, dis, row_off, csr, b1, W2, h2);
  k_agg2<<<N / 32, 256, 0, stream>>>(h2, dis, row_off, csr, b2, out2);
  k_readout<<<B, 256, 0, stream>>>(out2, gbuf, NPG);
  k_mlp<<<1, 64, 0, stream>>>(gbuf, W3, b3, W4, b4, (float*)d_out, B);
}

// Round 4
// 1349.145 us; speedup vs baseline: 1.2323x; 1.2323x over previous
//
#include <hip/hip_runtime.h>
#include <cstdint>

__device__ __forceinline__ float leaky(float v) { return v > 0.f ? v : 0.2f * v; }

// ---------------- CSR build ----------------

__global__ __launch_bounds__(256) void k_count(const int* __restrict__ dst,
                                               int* __restrict__ indeg, int E) {
  int e = blockIdx.x * 256 + threadIdx.x;
  if (e < E) atomicAdd(&indeg[dst[e]], 1);
}

__global__ __launch_bounds__(256) void k_scan1(const int* __restrict__ indeg,
                                               int* __restrict__ bsums) {
  __shared__ int red[256];
  int t = threadIdx.x;
  int base = blockIdx.x * 1024;
  int s = indeg[base + t] + indeg[base + t + 256] + indeg[base + t + 512] + indeg[base + t + 768];
  red[t] = s;
  __syncthreads();
  for (int off = 128; off > 0; off >>= 1) {
    if (t < off) red[t] += red[t + off];
    __syncthreads();
  }
  if (t == 0) bsums[blockIdx.x] = red[0];
}

__global__ __launch_bounds__(256) void k_scan2(int* __restrict__ bsums, int* __restrict__ row_off,
                                               int N, int E, int nb) {
  __shared__ int sc[256];
  int t = threadIdx.x;
  int v = (t < nb) ? bsums[t] : 0;
  sc[t] = v;
  __syncthreads();
  for (int off = 1; off < 256; off <<= 1) {
    int u = (t >= off) ? sc[t - off] : 0;
    __syncthreads();
    sc[t] += u;
    __syncthreads();
  }
  if (t < nb) bsums[t] = (t == 0) ? 0 : sc[t - 1];
  if (t == 0) row_off[N] = E;
}

__global__ __launch_bounds__(256) void k_scan3(const int* __restrict__ indeg,
                                               const int* __restrict__ bsums,
                                               int* __restrict__ row_off,
                                               int* __restrict__ cursor,
                                               float* __restrict__ dis) {
  __shared__ int sc[256];
  int t = threadIdx.x;
  int base = blockIdx.x * 1024;
  int4 d = *(const int4*)(indeg + base + 4 * t);
  int tot = d.x + d.y + d.z + d.w;
  sc[t] = tot;
  __syncthreads();
  for (int off = 1; off < 256; off <<= 1) {
    int u = (t >= off) ? sc[t - off] : 0;
    __syncthreads();
    sc[t] += u;
    __syncthreads();
  }
  int toff = bsums[blockIdx.x] + ((t == 0) ? 0 : sc[t - 1]);
  int4 ro;
  ro.x = toff;
  ro.y = toff + d.x;
  ro.z = toff + d.x + d.y;
  ro.w = toff + d.x + d.y + d.z;
  *(int4*)(row_off + base + 4 * t) = ro;
  *(int4*)(cursor + base + 4 * t) = ro;
  float4 dv;
  dv.x = rsqrtf((float)(d.x + 1));
  dv.y = rsqrtf((float)(d.y + 1));
  dv.z = rsqrtf((float)(d.z + 1));
  dv.w = rsqrtf((float)(d.w + 1));
  *(float4*)(dis + base + 4 * t) = dv;
}

__global__ __launch_bounds__(256) void k_fill(const int* __restrict__ ei,
                                              int* __restrict__ cursor,
                                              int* __restrict__ csr, int E) {
  int e = blockIdx.x * 256 + threadIdx.x;
  if (e < E) {
    int s = ei[e];
    int d = ei[E + e];
    int pos = atomicAdd(&cursor[d], 1);
    csr[pos] = s;
  }
}

// ---------------- Layer 1 projection: h1 = x @ W1  (N x 384 @ 384 x 32) ----------------
// 256 threads, 256 nodes/block, K-chunk = 32 floats (one full 128B line per row
// per chunk, fetched exactly once). Per thread: 4 consecutive nodes x 8 feats
// (acc = 32 VGPRs -> no spill; round-2 spilled 850MB of scratch at acc=64).

__global__ __launch_bounds__(256) void k_gemm1(const float* __restrict__ x,
                                               const float* __restrict__ W1,
                                               float* __restrict__ h1) {
  __shared__ float xl[32 * 256];  // [k][n]
  __shared__ float wl[32 * 32];   // [k][c]
  int t = threadIdx.x;
  size_t n0 = (size_t)blockIdx.x * 256;
  int fg8 = (t & 3) * 8;   // feature block
  int ng4 = (t >> 2) * 4;  // 4 consecutive nodes
  float acc[4][8];
#pragma unroll
  for (int i = 0; i < 4; i++)
#pragma unroll
    for (int c = 0; c < 8; c++) acc[i][c] = 0.f;

  for (int kc = 0; kc < 384; kc += 32) {
    __syncthreads();
    // stage x[k][n] transposed; 8 lanes cover one node's 128B chunk (full line)
#pragma unroll
    for (int g = 0; g < 2; g++) {
      float4 v[4];
#pragma unroll
      for (int i = 0; i < 4; i++) {
        int idx = g * 1024 + i * 256 + t;  // 0..2047
        int k4 = idx & 7;                  // float4 within 32-k chunk
        int n = idx >> 3;                  // node 0..255
        v[i] = *(const float4*)(x + (n0 + n) * 384 + kc + k4 * 4);
      }
#pragma unroll
      for (int i = 0; i < 4; i++) {
        int idx = g * 1024 + i * 256 + t;
        int k4 = idx & 7;
        int n = idx >> 3;
        xl[(k4 * 4 + 0) * 256 + n] = v[i].x;
        xl[(k4 * 4 + 1) * 256 + n] = v[i].y;
        xl[(k4 * 4 + 2) * 256 + n] = v[i].z;
        xl[(k4 * 4 + 3) * 256 + n] = v[i].w;
      }
    }
    ((float4*)wl)[t] = ((const float4*)(W1 + kc * 32))[t];  // 32x32 = 256 float4
    __syncthreads();
#pragma unroll
    for (int k = 0; k < 32; k++) {
      float4 xv = *(const float4*)&xl[k * 256 + ng4];
      float4 wa = *(const float4*)&wl[k * 32 + fg8];
      float4 wb = *(const float4*)&wl[k * 32 + fg8 + 4];
      float xr[4] = {xv.x, xv.y, xv.z, xv.w};
      float wr[8] = {wa.x, wa.y, wa.z, wa.w, wb.x, wb.y, wb.z, wb.w};
#pragma unroll
      for (int i = 0; i < 4; i++)
#pragma unroll
        for (int c = 0; c < 8; c++) acc[i][c] = fmaf(xr[i], wr[c], acc[i][c]);
    }
  }
#pragma unroll
  for (int i = 0; i < 4; i++) {
    float* dst = h1 + (n0 + ng4 + i) * 32 + fg8;
    *(float4*)dst = make_float4(acc[i][0], acc[i][1], acc[i][2], acc[i][3]);
    *((float4*)dst + 1) = make_float4(acc[i][4], acc[i][5], acc[i][6], acc[i][7]);
  }
}

// ---------------- Fused layer-1 aggregation + layer-2 projection ----------------
// One FULL wave per node: lanes split into two 32-lane halves, each half takes
// alternating neighbors (x2 unroll -> 4 independent gather chains per wave).
// After half-merge, project 32->8 via butterfly; out1 never touches memory.

__global__ __launch_bounds__(256) void k_agg1_fused(const float* __restrict__ h1,
                                                    const float* __restrict__ dis,
                                                    const int* __restrict__ row_off,
                                                    const int* __restrict__ csr,
                                                    const float* __restrict__ b1,
                                                    const float* __restrict__ W2,
                                                    float* __restrict__ h2) {
  __shared__ float w2s[256];
  int t = threadIdx.x;
  w2s[t] = W2[t];
  __syncthreads();
  int lane = t & 63;
  int half = lane >> 5;
  int j = lane & 31;
  int n = blockIdx.x * 4 + (t >> 6);
  int beg = row_off[n], end = row_off[n + 1];
  float dn = dis[n];
  float acc = half ? 0.f : h1[(size_t)n * 32 + j] * dn;  // self loop in half 0
  int p = beg + half;
  for (; p + 2 < end; p += 4) {
    int s0 = csr[p], s1 = csr[p + 2];
    float d0 = dis[s0], d1 = dis[s1];
    float v0 = h1[(size_t)s0 * 32 + j];
    float v1 = h1[(size_t)s1 * 32 + j];
    acc += v0 * d0 + v1 * d1;
  }
  if (p < end) {
    int s = csr[p];
    acc += h1[(size_t)s * 32 + j] * dis[s];
  }
  acc += __shfl_xor(acc, 32);  // merge halves
  float o = leaky(acc * dn + b1[j]);
  float pr[8];
#pragma unroll
  for (int c = 0; c < 8; c++) pr[c] = o * w2s[j * 8 + c];
#pragma unroll
  for (int off = 1; off < 32; off <<= 1) {
#pragma unroll
    for (int c = 0; c < 8; c++) pr[c] += __shfl_xor(pr[c], off);
  }
  if (j == 0) {
    float4 v = half ? make_float4(pr[4], pr[5], pr[6], pr[7])
                    : make_float4(pr[0], pr[1], pr[2], pr[3]);
    *(float4*)(h2 + (size_t)n * 8 + half * 4) = v;
  }
}

// ---------------- Layer 2 aggregation ----------------
// 16 lanes per node (two 8-lane halves on alternating neighbors, x2 unroll).

__global__ __launch_bounds__(256) void k_agg2(const float* __restrict__ h2,
                                              const float* __restrict__ dis,
                                              const int* __restrict__ row_off,
                                              const int* __restrict__ csr,
                                              const float* __restrict__ b2,
                                              float* __restrict__ out2) {
  int t = threadIdx.x;
  int j = t & 7;
  int sub = (t >> 3) & 1;
  int n = blockIdx.x * 16 + (t >> 4);
  int beg = row_off[n], end = row_off[n + 1];
  float dn = dis[n];
  float acc = sub ? 0.f : h2[(size_t)n * 8 + j] * dn;
  int p = beg + sub;
  for (; p + 2 < end; p += 4) {
    int s0 = csr[p], s1 = csr[p + 2];
    float d0 = dis[s0], d1 = dis[s1];
    acc += h2[(size_t)s0 * 8 + j] * d0 + h2[(size_t)s1 * 8 + j] * d1;
  }
  if (p < end) {
    int s = csr[p];
    acc += h2[(size_t)s * 8 + j] * dis[s];
  }
  acc += __shfl_xor(acc, 8);  // merge the two 8-lane halves
  if (!sub) out2[(size_t)n * 8 + j] = leaky(acc * dn + b2[j]);
}

// ---------------- Readout: per-graph mean over NPG nodes ----------------

__global__ __launch_bounds__(256) void k_readout(const float* __restrict__ out2,
                                                 float* __restrict__ g, int NPG) {
  __shared__ float red[256];
  int t = threadIdx.x;
  int j = t & 7, r0 = t >> 3;
  const float* base = out2 + (size_t)blockIdx.x * NPG * 8;
  float s = 0.f;
  for (int r = r0; r < NPG; r += 32) s += base[(size_t)r * 8 + j];
  red[t] = s;
  __syncthreads();
  if (t < 8) {
    float tot = 0.f;
    for (int q = 0; q < 32; q++) tot += red[t + 8 * q];
    g[blockIdx.x * 8 + t] = tot / (float)NPG;
  }
}

// ---------------- Final MLP: leaky(g@W3+b3)@W4 + b4 ----------------

__global__ __launch_bounds__(64) void k_mlp(const float* __restrict__ g,
                                            const float* __restrict__ W3,
                                            const float* __restrict__ b3,
                                            const float* __restrict__ W4,
                                            const float* __restrict__ b4,
                                            float* __restrict__ out, int B) {
  int b = threadIdx.x;
  if (b >= B) return;
  float gi[8], t1[8];
#pragma unroll
  for (int k = 0; k < 8; k++) gi[k] = g[b * 8 + k];
#pragma unroll
  for (int jj = 0; jj < 8; jj++) {
    float s = b3[jj];
#pragma unroll
    for (int k = 0; k < 8; k++) s = fmaf(gi[k], W3[k * 8 + jj], s);
    t1[jj] = leaky(s);
  }
#pragma unroll
  for (int jj = 0; jj < 2; jj++) {
    float s = b4[jj];
#pragma unroll
    for (int k = 0; k < 8; k++) s = fmaf(t1[k], W4[k * 2 + jj], s);
    out[b * 2 + jj] = s;
  }
}

extern "C" void kernel_launch(void* const* d_in, const int* in_sizes, int n_in,
                              void* d_out, int out_size, void* d_ws, size_t ws_size,
                              hipStream_t stream) {
  const float* x  = (const float*)d_in[0];
  const int*   ei = (const int*)d_in[1];  // [2][E]: row0=src, row1=dst
  const float* W1 = (const float*)d_in[3];
  const float* b1 = (const float*)d_in[4];
  const float* W2 = (const float*)d_in[5];
  const float* b2 = (const float*)d_in[6];
  const float* W3 = (const float*)d_in[7];
  const float* b3 = (const float*)d_in[8];
  const float* W4 = (const float*)d_in[9];
  const float* b4 = (const float*)d_in[10];

  const int E = in_sizes[1] / 2;
  const int N = in_sizes[2];
  const int B = out_size / 2;
  const int NPG = N / B;
  const int NB = N / 1024;

  // workspace layout with overflow guard
  size_t off = 0;
  auto place = [&](size_t bytes) {
    size_t p = off;
    off = (off + bytes + 255) & ~(size_t)255;
    return p;
  };
  size_t o_indeg   = place((size_t)N * 4);
  size_t o_dis     = place((size_t)N * 4);
  size_t o_row_off = place(((size_t)N + 1) * 4);
  size_t o_cursor  = place((size_t)N * 4);
  size_t o_csr     = place((size_t)E * 4);
  size_t o_bsums   = place(1024 * 4);
  size_t o_h1      = place((size_t)N * 32 * 4);
  size_t o_h2      = place((size_t)N * 8 * 4);
  size_t o_gbuf    = place((size_t)B * 8 * 4);
  if (off > ws_size) {
    hipMemsetAsync(d_out, 0, (size_t)out_size * 4, stream);
    return;
  }
  char* ws = (char*)d_ws;
  int*   indeg   = (int*)(ws + o_indeg);
  float* dis     = (float*)(ws + o_dis);
  int*   row_off = (int*)(ws + o_row_off);
  int*   cursor  = (int*)(ws + o_cursor);
  int*   csr     = (int*)(ws + o_csr);
  int*   bsums   = (int*)(ws + o_bsums);
  float* h1      = (float*)(ws + o_h1);
  float* h2      = (float*)(ws + o_h2);
  float* gbuf    = (float*)(ws + o_gbuf);
  float* out2    = h1;  // h1 dead after k_agg1_fused; safe alias

  hipMemsetAsync(indeg, 0, (size_t)N * 4, stream);
  k_count<<<(E + 255) / 256, 256, 0, stream>>>(ei + E, indeg, E);
  k_scan1<<<NB, 256, 0, stream>>>(indeg, bsums);
  k_scan2<<<1, 256, 0, stream>>>(bsums, row_off, N, E, NB);
  k_scan3<<<NB, 256, 0, stream>>>(indeg, bsums, row_off, cursor, dis);
  k_fill<<<(E + 255) / 256, 256, 0, stream>>>(ei, cursor, csr, E);
  k_gemm1<<<N / 256, 256, 0, stream>>>(x, W1, h1);
  k_agg1_fused<<<N / 4, 256, 0, stream>>>(h1, dis, row_off, csr, b1, W2, h2);
  k_agg2<<<N / 16, 256, 0, stream>>>(h2, dis, row_off, csr, b2, out2);
  k_readout<<<B, 256, 0, stream>>>(out2, gbuf, NPG);
  k_mlp<<<1, 64, 0, stream>>>(gbuf, W3, b3, W4, b4, (float*)d_out, B);
}

// Round 5
// 999.716 us; speedup vs baseline: 1.6630x; 1.3495x over previous
//
#include <hip/hip_runtime.h>
#include <cstdint>

__device__ __forceinline__ float leaky(float v) { return v > 0.f ? v : 0.2f * v; }

// ================= CSR build via two-level radix binning by dst =================
// Level 1: coarse buckets of 512 nodes (dst>>9). Per-(bucket,block) counts,
// exclusive scan, then scatter (src,dst) pairs into bucket regions (write runs
// are ~contiguous per block). Level 2: one block per bucket builds exact CSR
// with all scatter inside a 32KB L2-resident window. Replaces the round-4
// k_fill whose random 4B scatter across 16.8MB caused 265MB of HBM writeback.

#define NPB 512  // nodes per bucket (= 1<<9)

__global__ __launch_bounds__(256) void k_bin1(const int* __restrict__ dst,
                                              int* __restrict__ counts,
                                              int E, int CHUNK, int NBKT, int NBLK1) {
  __shared__ int hist[NPB];
  int t = threadIdx.x;
  int blk = blockIdx.x;
  for (int i = t; i < NBKT; i += 256) hist[i] = 0;
  __syncthreads();
  int e0 = blk * CHUNK;
  int e1 = min(e0 + CHUNK, E);
  for (int e = e0 + t; e < e1; e += 256) atomicAdd(&hist[dst[e] >> 9], 1);
  __syncthreads();
  for (int i = t; i < NBKT; i += 256) counts[i * NBLK1 + blk] = hist[i];
}

__global__ __launch_bounds__(256) void k_scan1(const int* __restrict__ cnt,
                                               int* __restrict__ bsums) {
  __shared__ int red[256];
  int t = threadIdx.x;
  int base = blockIdx.x * 1024;
  int s = cnt[base + t] + cnt[base + t + 256] + cnt[base + t + 512] + cnt[base + t + 768];
  red[t] = s;
  __syncthreads();
  for (int off = 128; off > 0; off >>= 1) {
    if (t < off) red[t] += red[t + off];
    __syncthreads();
  }
  if (t == 0) bsums[blockIdx.x] = red[0];
}

__global__ __launch_bounds__(256) void k_scan2(int* __restrict__ bsums, int* __restrict__ S,
                                               int total, int E, int nb) {
  __shared__ int sc[256];
  int t = threadIdx.x;
  int v = (t < nb) ? bsums[t] : 0;
  sc[t] = v;
  __syncthreads();
  for (int off = 1; off < 256; off <<= 1) {
    int u = (t >= off) ? sc[t - off] : 0;
    __syncthreads();
    sc[t] += u;
    __syncthreads();
  }
  if (t < nb) bsums[t] = (t == 0) ? 0 : sc[t - 1];
  if (t == 0) S[total] = E;
}

__global__ __launch_bounds__(256) void k_scan3(const int* __restrict__ cnt,
                                               const int* __restrict__ bsums,
                                               int* __restrict__ S) {
  __shared__ int sc[256];
  int t = threadIdx.x;
  int base = blockIdx.x * 1024;
  int4 d = *(const int4*)(cnt + base + 4 * t);
  int tot = d.x + d.y + d.z + d.w;
  sc[t] = tot;
  __syncthreads();
  for (int off = 1; off < 256; off <<= 1) {
    int u = (t >= off) ? sc[t - off] : 0;
    __syncthreads();
    sc[t] += u;
    __syncthreads();
  }
  int toff = bsums[blockIdx.x] + ((t == 0) ? 0 : sc[t - 1]);
  int4 ro;
  ro.x = toff;
  ro.y = toff + d.x;
  ro.z = toff + d.x + d.y;
  ro.w = toff + d.x + d.y + d.z;
  *(int4*)(S + base + 4 * t) = ro;
}

__global__ __launch_bounds__(256) void k_bin2(const int* __restrict__ ei,
                                              const int* __restrict__ S,
                                              int2* __restrict__ binned,
                                              int E, int CHUNK, int NBKT, int NBLK1) {
  __shared__ int cur[NPB];
  int t = threadIdx.x;
  int blk = blockIdx.x;
  for (int i = t; i < NBKT; i += 256) cur[i] = S[i * NBLK1 + blk];
  __syncthreads();
  int e0 = blk * CHUNK;
  int e1 = min(e0 + CHUNK, E);
  for (int e = e0 + t; e < e1; e += 256) {
    int s = ei[e];
    int d = ei[E + e];
    int pos = atomicAdd(&cur[d >> 9], 1);
    binned[pos] = make_int2(s, d);
  }
}

__global__ __launch_bounds__(256) void k_build(const int2* __restrict__ binned,
                                               const int* __restrict__ S,
                                               int* __restrict__ row_off,
                                               float* __restrict__ dis,
                                               int* __restrict__ csr,
                                               int E, int N, int NBKT, int NBLK1) {
  __shared__ int h[NPB];
  __shared__ int cur[NPB];
  int t = threadIdx.x;
  int b = blockIdx.x;
  int node0 = b * NPB;
  int begb = S[b * NBLK1];
  int endb = (b + 1 < NBKT) ? S[(b + 1) * NBLK1] : E;
  for (int i = t; i < NPB; i += 256) h[i] = 0;
  __syncthreads();
  for (int e = begb + t; e < endb; e += 256) atomicAdd(&h[binned[e].y - node0], 1);
  __syncthreads();
  // inclusive Hillis-Steele scan over 512 bins with 256 threads (2 elems/thread)
  for (int off = 1; off < NPB; off <<= 1) {
    int i0 = t, i1 = t + 256;
    int a0 = (i0 >= off) ? h[i0 - off] : 0;
    int a1 = (i1 >= off) ? h[i1 - off] : 0;
    __syncthreads();
    h[i0] += a0;
    h[i1] += a1;
    __syncthreads();
  }
  for (int i = t; i < NPB; i += 256) {
    int incl = h[i];
    int excl = i ? h[i - 1] : 0;
    row_off[node0 + i] = begb + excl;
    cur[i] = excl;
    dis[node0 + i] = rsqrtf((float)(incl - excl + 1));
  }
  __syncthreads();
  for (int e = begb + t; e < endb; e += 256) {
    int2 ed = binned[e];
    int pos = atomicAdd(&cur[ed.y - node0], 1);
    csr[begb + pos] = ed.x;
  }
  if (b == NBKT - 1 && t == 0) row_off[N] = E;
}

// ---------------- Layer 1 projection: h1 = x @ W1  (N x 384 @ 384 x 32) ----------------
// 256 threads, 256 nodes/block, K-chunk = 32 floats (one full 128B line per row
// per chunk, fetched exactly once). Per thread: 4 consecutive nodes x 8 feats.

__global__ __launch_bounds__(256) void k_gemm1(const float* __restrict__ x,
                                               const float* __restrict__ W1,
                                               float* __restrict__ h1) {
  __shared__ float xl[32 * 256];  // [k][n]
  __shared__ float wl[32 * 32];   // [k][c]
  int t = threadIdx.x;
  size_t n0 = (size_t)blockIdx.x * 256;
  int fg8 = (t & 3) * 8;   // feature block
  int ng4 = (t >> 2) * 4;  // 4 consecutive nodes
  float acc[4][8];
#pragma unroll
  for (int i = 0; i < 4; i++)
#pragma unroll
    for (int c = 0; c < 8; c++) acc[i][c] = 0.f;

  for (int kc = 0; kc < 384; kc += 32) {
    __syncthreads();
#pragma unroll
    for (int g = 0; g < 2; g++) {
      float4 v[4];
#pragma unroll
      for (int i = 0; i < 4; i++) {
        int idx = g * 1024 + i * 256 + t;  // 0..2047
        int k4 = idx & 7;                  // float4 within 32-k chunk
        int n = idx >> 3;                  // node 0..255
        v[i] = *(const float4*)(x + (n0 + n) * 384 + kc + k4 * 4);
      }
#pragma unroll
      for (int i = 0; i < 4; i++) {
        int idx = g * 1024 + i * 256 + t;
        int k4 = idx & 7;
        int n = idx >> 3;
        xl[(k4 * 4 + 0) * 256 + n] = v[i].x;
        xl[(k4 * 4 + 1) * 256 + n] = v[i].y;
        xl[(k4 * 4 + 2) * 256 + n] = v[i].z;
        xl[(k4 * 4 + 3) * 256 + n] = v[i].w;
      }
    }
    ((float4*)wl)[t] = ((const float4*)(W1 + kc * 32))[t];  // 32x32 = 256 float4
    __syncthreads();
#pragma unroll
    for (int k = 0; k < 32; k++) {
      float4 xv = *(const float4*)&xl[k * 256 + ng4];
      float4 wa = *(const float4*)&wl[k * 32 + fg8];
      float4 wb = *(const float4*)&wl[k * 32 + fg8 + 4];
      float xr[4] = {xv.x, xv.y, xv.z, xv.w};
      float wr[8] = {wa.x, wa.y, wa.z, wa.w, wb.x, wb.y, wb.z, wb.w};
#pragma unroll
      for (int i = 0; i < 4; i++)
#pragma unroll
        for (int c = 0; c < 8; c++) acc[i][c] = fmaf(xr[i], wr[c], acc[i][c]);
    }
  }
#pragma unroll
  for (int i = 0; i < 4; i++) {
    float* dst = h1 + (n0 + ng4 + i) * 32 + fg8;
    *(float4*)dst = make_float4(acc[i][0], acc[i][1], acc[i][2], acc[i][3]);
    *((float4*)dst + 1) = make_float4(acc[i][4], acc[i][5], acc[i][6], acc[i][7]);
  }
}

// ---------------- Fused layer-1 aggregation + layer-2 projection ----------------

__global__ __launch_bounds__(256) void k_agg1_fused(const float* __restrict__ h1,
                                                    const float* __restrict__ dis,
                                                    const int* __restrict__ row_off,
                                                    const int* __restrict__ csr,
                                                    const float* __restrict__ b1,
                                                    const float* __restrict__ W2,
                                                    float* __restrict__ h2) {
  __shared__ float w2s[256];
  int t = threadIdx.x;
  w2s[t] = W2[t];
  __syncthreads();
  int lane = t & 63;
  int half = lane >> 5;
  int j = lane & 31;
  int n = blockIdx.x * 4 + (t >> 6);
  int beg = row_off[n], end = row_off[n + 1];
  float dn = dis[n];
  float acc = half ? 0.f : h1[(size_t)n * 32 + j] * dn;  // self loop in half 0
  int p = beg + half;
  for (; p + 2 < end; p += 4) {
    int s0 = csr[p], s1 = csr[p + 2];
    float d0 = dis[s0], d1 = dis[s1];
    float v0 = h1[(size_t)s0 * 32 + j];
    float v1 = h1[(size_t)s1 * 32 + j];
    acc += v0 * d0 + v1 * d1;
  }
  if (p < end) {
    int s = csr[p];
    acc += h1[(size_t)s * 32 + j] * dis[s];
  }
  acc += __shfl_xor(acc, 32);  // merge halves
  float o = leaky(acc * dn + b1[j]);
  float pr[8];
#pragma unroll
  for (int c = 0; c < 8; c++) pr[c] = o * w2s[j * 8 + c];
#pragma unroll
  for (int off = 1; off < 32; off <<= 1) {
#pragma unroll
    for (int c = 0; c < 8; c++) pr[c] += __shfl_xor(pr[c], off);
  }
  if (j == 0) {
    float4 v = half ? make_float4(pr[4], pr[5], pr[6], pr[7])
                    : make_float4(pr[0], pr[1], pr[2], pr[3]);
    *(float4*)(h2 + (size_t)n * 8 + half * 4) = v;
  }
}

// ---------------- Layer 2 aggregation ----------------

__global__ __launch_bounds__(256) void k_agg2(const float* __restrict__ h2,
                                              const float* __restrict__ dis,
                                              const int* __restrict__ row_off,
                                              const int* __restrict__ csr,
                                              const float* __restrict__ b2,
                                              float* __restrict__ out2) {
  int t = threadIdx.x;
  int j = t & 7;
  int sub = (t >> 3) & 1;
  int n = blockIdx.x * 16 + (t >> 4);
  int beg = row_off[n], end = row_off[n + 1];
  float dn = dis[n];
  float acc = sub ? 0.f : h2[(size_t)n * 8 + j] * dn;
  int p = beg + sub;
  for (; p + 2 < end; p += 4) {
    int s0 = csr[p], s1 = csr[p + 2];
    float d0 = dis[s0], d1 = dis[s1];
    acc += h2[(size_t)s0 * 8 + j] * d0 + h2[(size_t)s1 * 8 + j] * d1;
  }
  if (p < end) {
    int s = csr[p];
    acc += h2[(size_t)s * 8 + j] * dis[s];
  }
  acc += __shfl_xor(acc, 8);  // merge the two 8-lane halves
  if (!sub) out2[(size_t)n * 8 + j] = leaky(acc * dn + b2[j]);
}

// ---------------- Readout: per-graph mean over NPG nodes ----------------

__global__ __launch_bounds__(256) void k_readout(const float* __restrict__ out2,
                                                 float* __restrict__ g, int NPG) {
  __shared__ float red[256];
  int t = threadIdx.x;
  int j = t & 7, r0 = t >> 3;
  const float* base = out2 + (size_t)blockIdx.x * NPG * 8;
  float s = 0.f;
  for (int r = r0; r < NPG; r += 32) s += base[(size_t)r * 8 + j];
  red[t] = s;
  __syncthreads();
  if (t < 8) {
    float tot = 0.f;
    for (int q = 0; q < 32; q++) tot += red[t + 8 * q];
    g[blockIdx.x * 8 + t] = tot / (float)NPG;
  }
}

// ---------------- Final MLP: leaky(g@W3+b3)@W4 + b4 ----------------

__global__ __launch_bounds__(64) void k_mlp(const float* __restrict__ g,
                                            const float* __restrict__ W3,
                                            const float* __restrict__ b3,
                                            const float* __restrict__ W4,
                                            const float* __restrict__ b4,
                                            float* __restrict__ out, int B) {
  int b = threadIdx.x;
  if (b >= B) return;
  float gi[8], t1[8];
#pragma unroll
  for (int k = 0; k < 8; k++) gi[k] = g[b * 8 + k];
#pragma unroll
  for (int jj = 0; jj < 8; jj++) {
    float s = b3[jj];
#pragma unroll
    for (int k = 0; k < 8; k++) s = fmaf(gi[k], W3[k * 8 + jj], s);
    t1[jj] = leaky(s);
  }
#pragma unroll
  for (int jj = 0; jj < 2; jj++) {
    float s = b4[jj];
#pragma unroll
    for (int k = 0; k < 8; k++) s = fmaf(t1[k], W4[k * 2 + jj], s);
    out[b * 2 + jj] = s;
  }
}

extern "C" void kernel_launch(void* const* d_in, const int* in_sizes, int n_in,
                              void* d_out, int out_size, void* d_ws, size_t ws_size,
                              hipStream_t stream) {
  const float* x  = (const float*)d_in[0];
  const int*   ei = (const int*)d_in[1];  // [2][E]: row0=src, row1=dst
  const float* W1 = (const float*)d_in[3];
  const float* b1 = (const float*)d_in[4];
  const float* W2 = (const float*)d_in[5];
  const float* b2 = (const float*)d_in[6];
  const float* W3 = (const float*)d_in[7];
  const float* b3 = (const float*)d_in[8];
  const float* W4 = (const float*)d_in[9];
  const float* b4 = (const float*)d_in[10];

  const int E = in_sizes[1] / 2;
  const int N = in_sizes[2];
  const int B = out_size / 2;
  const int NPG = N / B;

  const int NBKT  = N / NPB;                    // 512 coarse buckets
  const int NBLK1 = 512;                        // level-1 blocks
  const int CHUNK = (E + NBLK1 - 1) / NBLK1;    // edges per level-1 block
  const int SCN   = NBKT * NBLK1;               // counts matrix size (262144)
  const int NBS   = SCN / 1024;                 // scan1 blocks (256)

  // workspace layout with overflow guard
  size_t off = 0;
  auto place = [&](size_t bytes) {
    size_t p = off;
    off = (off + bytes + 255) & ~(size_t)255;
    return p;
  };
  size_t o_counts  = place((size_t)SCN * 4);
  size_t o_S       = place(((size_t)SCN + 1) * 4);
  size_t o_bsums   = place(1024 * 4);
  size_t o_dis     = place((size_t)N * 4);
  size_t o_row_off = place(((size_t)N + 1) * 4);
  size_t o_csr     = place((size_t)E * 4);
  size_t o_binned  = place((size_t)E * 8);      // aliased by h1 after k_build
  size_t o_h2      = place((size_t)N * 8 * 4);
  size_t o_gbuf    = place((size_t)B * 8 * 4);
  if (off > ws_size || N % NPB != 0) {
    hipMemsetAsync(d_out, 0, (size_t)out_size * 4, stream);
    return;
  }
  char* ws = (char*)d_ws;
  int*   counts  = (int*)(ws + o_counts);
  int*   S       = (int*)(ws + o_S);
  int*   bsums   = (int*)(ws + o_bsums);
  float* dis     = (float*)(ws + o_dis);
  int*   row_off = (int*)(ws + o_row_off);
  int*   csr     = (int*)(ws + o_csr);
  int2*  binned  = (int2*)(ws + o_binned);
  float* h1      = (float*)(ws + o_binned);     // alias: binned dead after k_build
  float* h2      = (float*)(ws + o_h2);
  float* gbuf    = (float*)(ws + o_gbuf);
  float* out2    = h1;                          // h1 dead after k_agg1_fused

  k_bin1<<<NBLK1, 256, 0, stream>>>(ei + E, counts, E, CHUNK, NBKT, NBLK1);
  k_scan1<<<NBS, 256, 0, stream>>>(counts, bsums);
  k_scan2<<<1, 256, 0, stream>>>(bsums, S, SCN, E, NBS);
  k_scan3<<<NBS, 256, 0, stream>>>(counts, bsums, S);
  k_bin2<<<NBLK1, 256, 0, stream>>>(ei, S, binned, E, CHUNK, NBKT, NBLK1);
  k_build<<<NBKT, 256, 0, stream>>>(binned, S, row_off, dis, csr, E, N, NBKT, NBLK1);
  k_gemm1<<<N / 256, 256, 0, stream>>>(x, W1, h1);
  k_agg1_fused<<<N / 4, 256, 0, stream>>>(h1, dis, row_off, csr, b1, W2, h2);
  k_agg2<<<N / 16, 256, 0, stream>>>(h2, dis, row_off, csr, b2, out2);
  k_readout<<<B, 256, 0, stream>>>(out2, gbuf, NPG);
  k_mlp<<<1, 64, 0, stream>>>(gbuf, W3, b3, W4, b4, (float*)d_out, B);
}

// Round 7
// 966.863 us; speedup vs baseline: 1.7195x; 1.0340x over previous
//
#include <hip/hip_runtime.h>
#include <cstdint>

__device__ __forceinline__ float leaky(float v) { return v > 0.f ? v : 0.2f * v; }
__device__ __forceinline__ unsigned short f2bf(float f) {
  unsigned int u = __float_as_uint(f);
  unsigned int r = (u + 0x7FFFu + ((u >> 16) & 1u)) >> 16;
  return (unsigned short)r;
}
__device__ __forceinline__ float bf2f(unsigned short h) {
  return __uint_as_float(((unsigned int)h) << 16);
}

// ================= CSR build via two-level radix binning by dst =================
#define NPB 512  // nodes per bucket (= 1<<9)

__global__ __launch_bounds__(256) void k_bin1(const int* __restrict__ dst,
                                              int* __restrict__ counts,
                                              int E, int CHUNK, int NBKT, int NBLK1) {
  __shared__ int hist[NPB];
  int t = threadIdx.x;
  int blk = blockIdx.x;
  for (int i = t; i < NBKT; i += 256) hist[i] = 0;
  __syncthreads();
  int e0 = blk * CHUNK;
  int e1 = min(e0 + CHUNK, E);
  for (int e = e0 + t; e < e1; e += 256) atomicAdd(&hist[dst[e] >> 9], 1);
  __syncthreads();
  for (int i = t; i < NBKT; i += 256) counts[i * NBLK1 + blk] = hist[i];
}

__global__ __launch_bounds__(256) void k_scan1(const int* __restrict__ cnt,
                                               int* __restrict__ bsums) {
  __shared__ int red[256];
  int t = threadIdx.x;
  int base = blockIdx.x * 1024;
  int s = cnt[base + t] + cnt[base + t + 256] + cnt[base + t + 512] + cnt[base + t + 768];
  red[t] = s;
  __syncthreads();
  for (int off = 128; off > 0; off >>= 1) {
    if (t < off) red[t] += red[t + off];
    __syncthreads();
  }
  if (t == 0) bsums[blockIdx.x] = red[0];
}

__global__ __launch_bounds__(256) void k_scan2(int* __restrict__ bsums, int* __restrict__ S,
                                               int total, int E, int nb) {
  __shared__ int sc[256];
  int t = threadIdx.x;
  int v = (t < nb) ? bsums[t] : 0;
  sc[t] = v;
  __syncthreads();
  for (int off = 1; off < 256; off <<= 1) {
    int u = (t >= off) ? sc[t - off] : 0;
    __syncthreads();
    sc[t] += u;
    __syncthreads();
  }
  if (t < nb) bsums[t] = (t == 0) ? 0 : sc[t - 1];
  if (t == 0) S[total] = E;
}

__global__ __launch_bounds__(256) void k_scan3(const int* __restrict__ cnt,
                                               const int* __restrict__ bsums,
                                               int* __restrict__ S) {
  __shared__ int sc[256];
  int t = threadIdx.x;
  int base = blockIdx.x * 1024;
  int4 d = *(const int4*)(cnt + base + 4 * t);
  int tot = d.x + d.y + d.z + d.w;
  sc[t] = tot;
  __syncthreads();
  for (int off = 1; off < 256; off <<= 1) {
    int u = (t >= off) ? sc[t - off] : 0;
    __syncthreads();
    sc[t] += u;
    __syncthreads();
  }
  int toff = bsums[blockIdx.x] + ((t == 0) ? 0 : sc[t - 1]);
  int4 ro;
  ro.x = toff;
  ro.y = toff + d.x;
  ro.z = toff + d.x + d.y;
  ro.w = toff + d.x + d.y + d.z;
  *(int4*)(S + base + 4 * t) = ro;
}

// scatter packed (src<<9 | dst&511) into coarse buckets
__global__ __launch_bounds__(256) void k_bin2(const int* __restrict__ ei,
                                              const int* __restrict__ S,
                                              int* __restrict__ binned,
                                              int E, int CHUNK, int NBKT, int NBLK1) {
  __shared__ int cur[NPB];
  int t = threadIdx.x;
  int blk = blockIdx.x;
  for (int i = t; i < NBKT; i += 256) cur[i] = S[i * NBLK1 + blk];
  __syncthreads();
  int e0 = blk * CHUNK;
  int e1 = min(e0 + CHUNK, E);
  for (int e = e0 + t; e < e1; e += 256) {
    int s = ei[e];
    int d = ei[E + e];
    int pos = atomicAdd(&cur[d >> 9], 1);
    binned[pos] = (s << 9) | (d & 511);
  }
}

__global__ __launch_bounds__(256) void k_build(const int* __restrict__ binned,
                                               const int* __restrict__ S,
                                               int* __restrict__ row_off,
                                               float* __restrict__ dis,
                                               int* __restrict__ csr,
                                               int E, int N, int NBKT, int NBLK1) {
  __shared__ int h[NPB];
  __shared__ int cur[NPB];
  int t = threadIdx.x;
  int b = blockIdx.x;
  int node0 = b * NPB;
  int begb = S[b * NBLK1];
  int endb = (b + 1 < NBKT) ? S[(b + 1) * NBLK1] : E;
  for (int i = t; i < NPB; i += 256) h[i] = 0;
  __syncthreads();
  for (int e = begb + t; e < endb; e += 256) atomicAdd(&h[binned[e] & 511], 1);
  __syncthreads();
  for (int off = 1; off < NPB; off <<= 1) {
    int i0 = t, i1 = t + 256;
    int a0 = (i0 >= off) ? h[i0 - off] : 0;
    int a1 = (i1 >= off) ? h[i1 - off] : 0;
    __syncthreads();
    h[i0] += a0;
    h[i1] += a1;
    __syncthreads();
  }
  for (int i = t; i < NPB; i += 256) {
    int incl = h[i];
    int excl = i ? h[i - 1] : 0;
    row_off[node0 + i] = begb + excl;
    cur[i] = excl;
    dis[node0 + i] = rsqrtf((float)(incl - excl + 1));
  }
  __syncthreads();
  for (int e = begb + t; e < endb; e += 256) {
    int ed = binned[e];
    int pos = atomicAdd(&cur[ed & 511], 1);
    csr[begb + pos] = ed >> 9;
  }
  if (b == NBKT - 1 && t == 0) row_off[N] = E;
}

// ---------------- Layer 1 projection: h1 = x @ W1 -> bf16 rows (64B/row) ----------------

__global__ __launch_bounds__(256) void k_gemm1(const float* __restrict__ x,
                                               const float* __restrict__ W1,
                                               unsigned short* __restrict__ h1b) {
  __shared__ float xl[32 * 256];  // [k][n]
  __shared__ float wl[32 * 32];   // [k][c]
  int t = threadIdx.x;
  size_t n0 = (size_t)blockIdx.x * 256;
  int fg8 = (t & 3) * 8;
  int ng4 = (t >> 2) * 4;
  float acc[4][8];
#pragma unroll
  for (int i = 0; i < 4; i++)
#pragma unroll
    for (int c = 0; c < 8; c++) acc[i][c] = 0.f;

  for (int kc = 0; kc < 384; kc += 32) {
    __syncthreads();
#pragma unroll
    for (int g = 0; g < 2; g++) {
      float4 v[4];
#pragma unroll
      for (int i = 0; i < 4; i++) {
        int idx = g * 1024 + i * 256 + t;
        int k4 = idx & 7;
        int n = idx >> 3;
        v[i] = *(const float4*)(x + (n0 + n) * 384 + kc + k4 * 4);
      }
#pragma unroll
      for (int i = 0; i < 4; i++) {
        int idx = g * 1024 + i * 256 + t;
        int k4 = idx & 7;
        int n = idx >> 3;
        xl[(k4 * 4 + 0) * 256 + n] = v[i].x;
        xl[(k4 * 4 + 1) * 256 + n] = v[i].y;
        xl[(k4 * 4 + 2) * 256 + n] = v[i].z;
        xl[(k4 * 4 + 3) * 256 + n] = v[i].w;
      }
    }
    ((float4*)wl)[t] = ((const float4*)(W1 + kc * 32))[t];
    __syncthreads();
#pragma unroll
    for (int k = 0; k < 32; k++) {
      float4 xv = *(const float4*)&xl[k * 256 + ng4];
      float4 wa = *(const float4*)&wl[k * 32 + fg8];
      float4 wb = *(const float4*)&wl[k * 32 + fg8 + 4];
      float xr[4] = {xv.x, xv.y, xv.z, xv.w};
      float wr[8] = {wa.x, wa.y, wa.z, wa.w, wb.x, wb.y, wb.z, wb.w};
#pragma unroll
      for (int i = 0; i < 4; i++)
#pragma unroll
        for (int c = 0; c < 8; c++) acc[i][c] = fmaf(xr[i], wr[c], acc[i][c]);
    }
  }
#pragma unroll
  for (int i = 0; i < 4; i++) {
    uint4 pk;
    pk.x = (unsigned)f2bf(acc[i][0]) | ((unsigned)f2bf(acc[i][1]) << 16);
    pk.y = (unsigned)f2bf(acc[i][2]) | ((unsigned)f2bf(acc[i][3]) << 16);
    pk.z = (unsigned)f2bf(acc[i][4]) | ((unsigned)f2bf(acc[i][5]) << 16);
    pk.w = (unsigned)f2bf(acc[i][6]) | ((unsigned)f2bf(acc[i][7]) << 16);
    *(uint4*)(h1b + (n0 + ng4 + i) * 32 + fg8) = pk;
  }
}

// ---------------- Fused layer-1 aggregation + layer-2 projection ----------------
// Wave per node; two 32-lane halves on alternating edges, 4-deep gather unroll.

__global__ __launch_bounds__(256) void k_agg1_fused(const unsigned short* __restrict__ h1b,
                                                    const float* __restrict__ dis,
                                                    const int* __restrict__ row_off,
                                                    const int* __restrict__ csr,
                                                    const float* __restrict__ b1,
                                                    const float* __restrict__ W2,
                                                    unsigned short* __restrict__ h2b) {
  __shared__ float w2s[256];
  int t = threadIdx.x;
  w2s[t] = W2[t];
  __syncthreads();
  int lane = t & 63;
  int half = lane >> 5;
  int j = lane & 31;
  int n = blockIdx.x * 4 + (t >> 6);
  int beg = row_off[n], end = row_off[n + 1];
  float dn = dis[n];
  float acc = half ? 0.f : bf2f(h1b[(size_t)n * 32 + j]) * dn;  // self loop in half 0
  int p = beg + half;
  for (; p + 6 < end; p += 8) {
    int s0 = csr[p], s1 = csr[p + 2], s2 = csr[p + 4], s3 = csr[p + 6];
    float d0 = dis[s0], d1 = dis[s1], d2 = dis[s2], d3 = dis[s3];
    float v0 = bf2f(h1b[(size_t)s0 * 32 + j]);
    float v1 = bf2f(h1b[(size_t)s1 * 32 + j]);
    float v2 = bf2f(h1b[(size_t)s2 * 32 + j]);
    float v3 = bf2f(h1b[(size_t)s3 * 32 + j]);
    acc += v0 * d0 + v1 * d1 + v2 * d2 + v3 * d3;
  }
  for (; p < end; p += 2) {
    int s = csr[p];
    acc += bf2f(h1b[(size_t)s * 32 + j]) * dis[s];
  }
  acc += __shfl_xor(acc, 32);  // merge halves
  float o = leaky(acc * dn + b1[j]);
  float pr[8];
#pragma unroll
  for (int c = 0; c < 8; c++) pr[c] = o * w2s[j * 8 + c];
#pragma unroll
  for (int off = 1; off < 32; off <<= 1) {
#pragma unroll
    for (int c = 0; c < 8; c++) pr[c] += __shfl_xor(pr[c], off);
  }
  if (lane == 0) {
    uint4 pk;
    pk.x = (unsigned)f2bf(pr[0]) | ((unsigned)f2bf(pr[1]) << 16);
    pk.y = (unsigned)f2bf(pr[2]) | ((unsigned)f2bf(pr[3]) << 16);
    pk.z = (unsigned)f2bf(pr[4]) | ((unsigned)f2bf(pr[5]) << 16);
    pk.w = (unsigned)f2bf(pr[6]) | ((unsigned)f2bf(pr[7]) << 16);
    *(uint4*)(h2b + (size_t)n * 8) = pk;
  }
}

// ---------------- Layer 2 aggregation fused with graph-mean readout ----------------
// 16 lanes per node (two 8-lane subs, 4-deep unroll); 16 nodes/block; block
// partial-sums per feature -> one atomicAdd per (block,feat) into gbuf.

__global__ __launch_bounds__(256) void k_agg2r(const unsigned short* __restrict__ h2b,
                                               const float* __restrict__ dis,
                                               const int* __restrict__ row_off,
                                               const int* __restrict__ csr,
                                               const float* __restrict__ b2,
                                               float* __restrict__ gbuf, int NPG) {
  __shared__ float red[128];
  int t = threadIdx.x;
  int j = t & 7;
  int sub = (t >> 3) & 1;
  int nl = t >> 4;  // 0..15
  int n = blockIdx.x * 16 + nl;
  int beg = row_off[n], end = row_off[n + 1];
  float dn = dis[n];
  float acc = sub ? 0.f : bf2f(h2b[(size_t)n * 8 + j]) * dn;
  int p = beg + sub;
  for (; p + 6 < end; p += 8) {
    int s0 = csr[p], s1 = csr[p + 2], s2 = csr[p + 4], s3 = csr[p + 6];
    float d0 = dis[s0], d1 = dis[s1], d2 = dis[s2], d3 = dis[s3];
    float v0 = bf2f(h2b[(size_t)s0 * 8 + j]);
    float v1 = bf2f(h2b[(size_t)s1 * 8 + j]);
    float v2 = bf2f(h2b[(size_t)s2 * 8 + j]);
    float v3 = bf2f(h2b[(size_t)s3 * 8 + j]);
    acc += v0 * d0 + v1 * d1 + v2 * d2 + v3 * d3;
  }
  for (; p < end; p += 2) {
    int s = csr[p];
    acc += bf2f(h2b[(size_t)s * 8 + j]) * dis[s];
  }
  acc += __shfl_xor(acc, 8);  // merge subs
  if (sub == 0) red[nl * 8 + j] = leaky(acc * dn + b2[j]);
  __syncthreads();
  if (t < 8) {
    float s = 0.f;
#pragma unroll
    for (int i = 0; i < 16; i++) s += red[i * 8 + t];
    int graph = (blockIdx.x * 16) / NPG;
    atomicAdd(&gbuf[graph * 8 + t], s);
  }
}

// ---------------- Final MLP: leaky((g/NPG)@W3+b3)@W4 + b4 ----------------

__global__ __launch_bounds__(64) void k_mlp(const float* __restrict__ g,
                                            const float* __restrict__ W3,
                                            const float* __restrict__ b3,
                                            const float* __restrict__ W4,
                                            const float* __restrict__ b4,
                                            float* __restrict__ out, int B, int NPG) {
  int b = threadIdx.x;
  if (b >= B) return;
  float inv = 1.0f / (float)NPG;
  float gi[8], t1[8];
#pragma unroll
  for (int k = 0; k < 8; k++) gi[k] = g[b * 8 + k] * inv;
#pragma unroll
  for (int jj = 0; jj < 8; jj++) {
    float s = b3[jj];
#pragma unroll
    for (int k = 0; k < 8; k++) s = fmaf(gi[k], W3[k * 8 + jj], s);
    t1[jj] = leaky(s);
  }
#pragma unroll
  for (int jj = 0; jj < 2; jj++) {
    float s = b4[jj];
#pragma unroll
    for (int k = 0; k < 8; k++) s = fmaf(t1[k], W4[k * 2 + jj], s);
    out[b * 2 + jj] = s;
  }
}

extern "C" void kernel_launch(void* const* d_in, const int* in_sizes, int n_in,
                              void* d_out, int out_size, void* d_ws, size_t ws_size,
                              hipStream_t stream) {
  const float* x  = (const float*)d_in[0];
  const int*   ei = (const int*)d_in[1];  // [2][E]: row0=src, row1=dst
  const float* W1 = (const float*)d_in[3];
  const float* b1 = (const float*)d_in[4];
  const float* W2 = (const float*)d_in[5];
  const float* b2 = (const float*)d_in[6];
  const float* W3 = (const float*)d_in[7];
  const float* b3 = (const float*)d_in[8];
  const float* W4 = (const float*)d_in[9];
  const float* b4 = (const float*)d_in[10];

  const int E = in_sizes[1] / 2;
  const int N = in_sizes[2];
  const int B = out_size / 2;
  const int NPG = N / B;

  const int NBKT  = N / NPB;                  // 512 coarse buckets
  const int NBLK1 = 512;                      // level-1 blocks
  const int CHUNK = (E + NBLK1 - 1) / NBLK1;
  const int SCN   = NBKT * NBLK1;
  const int NBS   = SCN / 1024;

  size_t off = 0;
  auto place = [&](size_t bytes) {
    size_t p = off;
    off = (off + bytes + 255) & ~(size_t)255;
    return p;
  };
  size_t o_counts  = place((size_t)SCN * 4);
  size_t o_S       = place(((size_t)SCN + 1) * 4);
  size_t o_bsums   = place(1024 * 4);
  size_t o_dis     = place((size_t)N * 4);
  size_t o_row_off = place(((size_t)N + 1) * 4);
  size_t o_csr     = place((size_t)E * 4);
  size_t o_binned  = place((size_t)E * 4 > (size_t)N * 64 ? (size_t)E * 4 : (size_t)N * 64);
  size_t o_h2      = place((size_t)N * 8 * 2);
  size_t o_gbuf    = place((size_t)B * 8 * 4);
  if (off > ws_size || N % NPB != 0) {
    hipMemsetAsync(d_out, 0, (size_t)out_size * 4, stream);
    return;
  }
  char* ws = (char*)d_ws;
  int*   counts  = (int*)(ws + o_counts);
  int*   S       = (int*)(ws + o_S);
  int*   bsums   = (int*)(ws + o_bsums);
  float* dis     = (float*)(ws + o_dis);
  int*   row_off = (int*)(ws + o_row_off);
  int*   csr     = (int*)(ws + o_csr);
  int*   binned  = (int*)(ws + o_binned);
  unsigned short* h1b = (unsigned short*)(ws + o_binned);  // alias: binned dead after k_build
  unsigned short* h2b = (unsigned short*)(ws + o_h2);
  float* gbuf    = (float*)(ws + o_gbuf);

  hipMemsetAsync(gbuf, 0, (size_t)B * 8 * 4, stream);
  k_bin1<<<NBLK1, 256, 0, stream>>>(ei + E, counts, E, CHUNK, NBKT, NBLK1);
  k_scan1<<<NBS, 256, 0, stream>>>(counts, bsums);
  k_scan2<<<1, 256, 0, stream>>>(bsums, S, SCN, E, NBS);
  k_scan3<<<NBS, 256, 0, stream>>>(counts, bsums, S);
  k_bin2<<<NBLK1, 256, 0, stream>>>(ei, S, binned, E, CHUNK, NBKT, NBLK1);
  k_build<<<NBKT, 256, 0, stream>>>(binned, S, row_off, dis, csr, E, N, NBKT, NBLK1);
  k_gemm1<<<N / 256, 256, 0, stream>>>(x, W1, h1b);
  k_agg1_fused<<<N / 4, 256, 0, stream>>>(h1b, dis, row_off, csr, b1, W2, h2b);
  k_agg2r<<<N / 16, 256, 0, stream>>>(h2b, dis, row_off, csr, b2, gbuf, NPG);
  k_mlp<<<1, 64, 0, stream>>>(gbuf, W3, b3, W4, b4, (float*)d_out, B, NPG);
}